// Round 1
// baseline (123.340 us; speedup 1.0000x reference)
//
#include <hip/hip_runtime.h>

// Problem: B=4096, D=2, H=2048.
// e = sum_d enc[b,d,h]; d = sum_d dec[b,d,h]; S = e @ d^T (4096x4096)
// M = S on diag, -S off diag; LL = log_sigmoid(M)
// logLoss = -(sum(LL) + 39*sum(diag LL))/B ; diagonalLoss = -40*sum(diag LL)/B

#define BDIM 4096
#define HDIM 2048
#define BM 128
#define BN 128
#define BK 32

typedef __attribute__((ext_vector_type(8))) short bf16x8;
typedef __attribute__((ext_vector_type(4))) float f32x4;

__device__ __forceinline__ unsigned short f2bf(float f) {
    unsigned int u = __float_as_uint(f);
    unsigned int r = (u + 0x7FFFu + ((u >> 16) & 1u)) >> 16;
    return (unsigned short)r;
}

__device__ __forceinline__ void gll16(const void* g, void* l) {
    __builtin_amdgcn_global_load_lds(
        (const __attribute__((address_space(1))) unsigned int*)g,
        (__attribute__((address_space(3))) unsigned int*)l,
        16, 0, 0);
}

// ---------------- Kernel 1: D-reduce + cast to bf16 ----------------
// enc [4096][2][2048] f32 -> eb [4096][2048] bf16 (same for dec->db)
// 1048576 threads, 8 h-elements each.
__global__ void reduce_cast(const float4* __restrict__ enc,
                            const float4* __restrict__ dec,
                            uint4* __restrict__ eb,
                            uint4* __restrict__ db) {
    int idx = blockIdx.x * blockDim.x + threadIdx.x;   // 0..1048575
    int b  = idx >> 8;          // row
    int ch = idx & 255;         // 8-elem chunk within row
    int f4 = b * 1024 + ch * 2; // float4 index of layer 0

    {
        float4 a0 = enc[f4],       a1 = enc[f4 + 1];
        float4 c0 = enc[f4 + 512], c1 = enc[f4 + 512 + 1];
        uint4 o;
        o.x = (unsigned int)f2bf(a0.x + c0.x) | ((unsigned int)f2bf(a0.y + c0.y) << 16);
        o.y = (unsigned int)f2bf(a0.z + c0.z) | ((unsigned int)f2bf(a0.w + c0.w) << 16);
        o.z = (unsigned int)f2bf(a1.x + c1.x) | ((unsigned int)f2bf(a1.y + c1.y) << 16);
        o.w = (unsigned int)f2bf(a1.z + c1.z) | ((unsigned int)f2bf(a1.w + c1.w) << 16);
        eb[idx] = o;
    }
    {
        float4 a0 = dec[f4],       a1 = dec[f4 + 1];
        float4 c0 = dec[f4 + 512], c1 = dec[f4 + 512 + 1];
        uint4 o;
        o.x = (unsigned int)f2bf(a0.x + c0.x) | ((unsigned int)f2bf(a0.y + c0.y) << 16);
        o.y = (unsigned int)f2bf(a0.z + c0.z) | ((unsigned int)f2bf(a0.w + c0.w) << 16);
        o.z = (unsigned int)f2bf(a1.x + c1.x) | ((unsigned int)f2bf(a1.y + c1.y) << 16);
        o.w = (unsigned int)f2bf(a1.z + c1.z) | ((unsigned int)f2bf(a1.w + c1.w) << 16);
        db[idx] = o;
    }
}

// ---------------- Kernel 2: fused GEMM + log-sigmoid reduce ----------------
// S-tile 128x128 per block, bf16 MFMA 16x16x32, 4 waves (2x2), 4x4 frags/wave.
// Never materializes S; accumulates sum(LL) and sum(diag LL) per block.
__global__ __launch_bounds__(256) void gemm_reduce(
        const unsigned short* __restrict__ eb,
        const unsigned short* __restrict__ db,
        float* __restrict__ pall,
        float* __restrict__ pdiag) {
    __shared__ __align__(16) unsigned short As[BM * BK];
    __shared__ __align__(16) unsigned short Bs[BN * BK];
    __shared__ float red[8];

    const int t    = threadIdx.x;
    const int lane = t & 63;
    const int wid  = t >> 6;
    const int wr   = wid >> 1, wc = wid & 1;
    const int bm   = blockIdx.y, bn = blockIdx.x;
    const int row0 = bm * BM, col0 = bn * BN;

    // staging: thread t loads 16B (8 bf16); 4 threads/row, 64 rows/issue
    const int sr = t >> 2;
    const int sc = (t & 3) * 8;

    const int fr = lane & 15;         // fragment row (A) / col (B)
    const int kg = (lane >> 4) * 8;   // k-group base within BK

    f32x4 acc[4][4] = {};

    for (int kt = 0; kt < HDIM; kt += BK) {
        gll16(eb + (size_t)(row0 + sr)      * HDIM + kt + sc, &As[sr * BK + sc]);
        gll16(eb + (size_t)(row0 + 64 + sr) * HDIM + kt + sc, &As[(64 + sr) * BK + sc]);
        gll16(db + (size_t)(col0 + sr)      * HDIM + kt + sc, &Bs[sr * BK + sc]);
        gll16(db + (size_t)(col0 + 64 + sr) * HDIM + kt + sc, &Bs[(64 + sr) * BK + sc]);
        __syncthreads();

        bf16x8 a[4], b[4];
#pragma unroll
        for (int m = 0; m < 4; ++m)
            a[m] = *(const bf16x8*)&As[(wr * 64 + m * 16 + fr) * BK + kg];
#pragma unroll
        for (int n = 0; n < 4; ++n)
            b[n] = *(const bf16x8*)&Bs[(wc * 64 + n * 16 + fr) * BK + kg];
#pragma unroll
        for (int m = 0; m < 4; ++m)
#pragma unroll
            for (int n = 0; n < 4; ++n)
                acc[m][n] = __builtin_amdgcn_mfma_f32_16x16x32_bf16(a[m], b[n], acc[m][n], 0, 0, 0);
        __syncthreads();
    }

    // epilogue: C/D layout col=lane&15, row=(lane>>4)*4+reg (m89-verified)
    const int rbase = row0 + wr * 64 + ((lane >> 4) * 4);
    const int cbase = col0 + wc * 64 + fr;
    float s_all = 0.f, s_diag = 0.f;
#pragma unroll
    for (int m = 0; m < 4; ++m) {
#pragma unroll
        for (int n = 0; n < 4; ++n) {
#pragma unroll
            for (int r = 0; r < 4; ++r) {
                float S = acc[m][n][r];
                int row = rbase + m * 16 + r;
                int col = cbase + n * 16;
                bool dg = (row == col);
                float x = dg ? S : -S;
                // stable log_sigmoid(x) = min(x,0) - log(1+exp(-|x|))
                float ll = fminf(x, 0.f) - __logf(1.f + __expf(-fabsf(x)));
                s_all += ll;
                if (dg) s_diag += ll;
            }
        }
    }

    // wave reduce (64 lanes)
#pragma unroll
    for (int off = 32; off; off >>= 1) {
        s_all  += __shfl_down(s_all, off);
        s_diag += __shfl_down(s_diag, off);
    }
    if (lane == 0) { red[wid] = s_all; red[4 + wid] = s_diag; }
    __syncthreads();
    if (t == 0) {
        int bflat = bm * gridDim.x + bn;
        pall[bflat]  = red[0] + red[1] + red[2] + red[3];
        pdiag[bflat] = red[4] + red[5] + red[6] + red[7];
    }
}

// ---------------- Kernel 3: finalize ----------------
__global__ void finalize(const float* __restrict__ pall,
                         const float* __restrict__ pdiag,
                         float* __restrict__ out) {
    float a = 0.f, d = 0.f;
    for (int i = threadIdx.x; i < 1024; i += 256) { a += pall[i]; d += pdiag[i]; }
#pragma unroll
    for (int off = 32; off; off >>= 1) {
        a += __shfl_down(a, off);
        d += __shfl_down(d, off);
    }
    __shared__ float r[8];
    int wid = threadIdx.x >> 6, lane = threadIdx.x & 63;
    if (lane == 0) { r[wid] = a; r[4 + wid] = d; }
    __syncthreads();
    if (threadIdx.x == 0) {
        float A = r[0] + r[1] + r[2] + r[3];
        float D = r[4] + r[5] + r[6] + r[7];
        out[0] = -(A + 39.f * D) / (float)BDIM;  // logLoss
        out[1] = -(40.f * D) / (float)BDIM;      // diagonalLoss
    }
}

extern "C" void kernel_launch(void* const* d_in, const int* in_sizes, int n_in,
                              void* d_out, int out_size, void* d_ws, size_t ws_size,
                              hipStream_t stream) {
    const float* enc = (const float*)d_in[0];
    const float* dec = (const float*)d_in[1];
    float* out = (float*)d_out;

    char* ws = (char*)d_ws;
    // ws layout: eb 16MB | db 16MB | pall 4KB | pdiag 4KB   (needs 32MB+8KB)
    unsigned short* eb = (unsigned short*)ws;
    unsigned short* db = (unsigned short*)(ws + (size_t)16 * 1024 * 1024);
    float* pall  = (float*)(ws + (size_t)32 * 1024 * 1024);
    float* pdiag = pall + 1024;

    reduce_cast<<<4096, 256, 0, stream>>>(
        (const float4*)enc, (const float4*)dec, (uint4*)eb, (uint4*)db);

    dim3 grid(BDIM / BN, BDIM / BM);  // (32, 32)
    gemm_reduce<<<grid, 256, 0, stream>>>(eb, db, pall, pdiag);

    finalize<<<1, 256, 0, stream>>>(pall, pdiag, out);
}

// Round 2
// 95.270 us; speedup vs baseline: 1.2946x; 1.2946x over previous
//
#include <hip/hip_runtime.h>

// Problem: B=4096, D=2, H=2048.
// e = sum_d enc[b,d,h]; d = sum_d dec[b,d,h]; S = e @ d^T (4096x4096)
// M = S on diag, -S off diag; LL = log_sigmoid(M)
// logLoss = -(sum(LL) + 39*sum(diag LL))/B ; diagonalLoss = -40*sum(diag LL)/B

#define BDIM 4096
#define HDIM 2048
#define BM 256
#define BN 256
#define BK 64
#define NT (HDIM / BK)   // 32 K-tiles
#define NBLK ((BDIM/BM) * (BDIM/BN))  // 256 blocks

typedef __attribute__((ext_vector_type(8))) short bf16x8;
typedef __attribute__((ext_vector_type(4))) float f32x4;

__device__ __forceinline__ unsigned short f2bf(float f) {
    unsigned int u = __float_as_uint(f);
    unsigned int r = (u + 0x7FFFu + ((u >> 16) & 1u)) >> 16;
    return (unsigned short)r;
}

__device__ __forceinline__ void gll16(const void* g, void* l) {
    __builtin_amdgcn_global_load_lds(
        (const __attribute__((address_space(1))) unsigned int*)g,
        (__attribute__((address_space(3))) unsigned int*)l,
        16, 0, 0);
}

// ---------------- Kernel 1: D-reduce + cast to bf16 ----------------
__global__ void reduce_cast(const float4* __restrict__ enc,
                            const float4* __restrict__ dec,
                            uint4* __restrict__ eb,
                            uint4* __restrict__ db) {
    int idx = blockIdx.x * blockDim.x + threadIdx.x;   // 0..1048575
    int b  = idx >> 8;
    int ch = idx & 255;
    int f4 = b * 1024 + ch * 2;

    {
        float4 a0 = enc[f4],       a1 = enc[f4 + 1];
        float4 c0 = enc[f4 + 512], c1 = enc[f4 + 512 + 1];
        uint4 o;
        o.x = (unsigned int)f2bf(a0.x + c0.x) | ((unsigned int)f2bf(a0.y + c0.y) << 16);
        o.y = (unsigned int)f2bf(a0.z + c0.z) | ((unsigned int)f2bf(a0.w + c0.w) << 16);
        o.z = (unsigned int)f2bf(a1.x + c1.x) | ((unsigned int)f2bf(a1.y + c1.y) << 16);
        o.w = (unsigned int)f2bf(a1.z + c1.z) | ((unsigned int)f2bf(a1.w + c1.w) << 16);
        eb[idx] = o;
    }
    {
        float4 a0 = dec[f4],       a1 = dec[f4 + 1];
        float4 c0 = dec[f4 + 512], c1 = dec[f4 + 512 + 1];
        uint4 o;
        o.x = (unsigned int)f2bf(a0.x + c0.x) | ((unsigned int)f2bf(a0.y + c0.y) << 16);
        o.y = (unsigned int)f2bf(a0.z + c0.z) | ((unsigned int)f2bf(a0.w + c0.w) << 16);
        o.z = (unsigned int)f2bf(a1.x + c1.x) | ((unsigned int)f2bf(a1.y + c1.y) << 16);
        o.w = (unsigned int)f2bf(a1.z + c1.z) | ((unsigned int)f2bf(a1.w + c1.w) << 16);
        db[idx] = o;
    }
}

// ---------------- Kernel 2: 256x256 pipelined GEMM + fused log-sigmoid ----------------
// 8 waves (2M x 4N), per-wave 128x64 output, acc[8][4] f32x4.
// LDS: 2 buffers x (A 256x64 + B 256x64) bf16 = 128 KiB, XOR-swizzled slots.
// Pipeline: compute buf[cur] (4 phases, no internal barriers) -> s_barrier ->
//           issue stage(t+2 -> buf[cur]) -> vmcnt(8) (tile t+1 landed) -> s_barrier.
__global__ __launch_bounds__(512, 2) void gemm_reduce(
        const unsigned short* __restrict__ eb,
        const unsigned short* __restrict__ db,
        float* __restrict__ pall,
        float* __restrict__ pdiag) {
    __shared__ __align__(16) unsigned short lds[2 * 2 * BM * BK];  // 128 KiB

    const int tid  = threadIdx.x;
    const int lane = tid & 63;
    const int wid  = tid >> 6;          // 0..7
    const int wr   = wid >> 2;          // 0..1  (M)
    const int wc   = wid & 3;           // 0..3  (N)
    const int bm   = blockIdx.y, bn = blockIdx.x;
    const int row0 = bm * BM, col0 = bn * BN;

    const int fr = lane & 15;           // fragment row
    const int kg = (lane >> 4) * 8;     // k-group base within 32

    // staging geometry: thread covers (row = i*64 + tid>>3, slot = tid&7),
    // global col pre-swizzled so LDS[row][slot] = global slot (slot ^ (row&7))
    const int str = tid >> 3;                           // 0..63
    const int swc = (((tid & 7) ^ (str & 7)) << 3);     // element col offset

    f32x4 acc[8][4] = {};
    bf16x8 a[4][2], b0[2][2], b1[2][2];

#define STAGE(buf, kt)                                                          \
    {                                                                           \
        unsigned short* As_ = lds + (buf) * 32768;                              \
        unsigned short* Bs_ = As_ + 16384;                                      \
        _Pragma("unroll")                                                       \
        for (int i = 0; i < 4; ++i)                                             \
            gll16(eb + (size_t)(row0 + i * 64 + str) * HDIM + (kt) + swc,       \
                  As_ + i * 4096 + tid * 8);                                    \
        _Pragma("unroll")                                                       \
        for (int i = 0; i < 4; ++i)                                             \
            gll16(db + (size_t)(col0 + i * 64 + str) * HDIM + (kt) + swc,       \
                  Bs_ + i * 4096 + tid * 8);                                    \
    }

    // swizzled fragment read: row r, k-col c (multiple of 8)
#define LDF(base, r, c) \
    (*(const bf16x8*)((base) + (r) * 64 + (((((c) >> 3)) ^ ((r) & 7)) << 3)))

    // prologue: tile0 -> buf0, tile1 -> buf1
    STAGE(0, 0);
    STAGE(1, BK);
    asm volatile("s_waitcnt vmcnt(8)" ::: "memory");   // tile0 landed
    __builtin_amdgcn_s_barrier();

    for (int ti = 0; ti < NT; ++ti) {
        const int cur = ti & 1;
        const unsigned short* As_ = lds + cur * 32768;
        const unsigned short* Bs_ = As_ + 16384;

        // ---- Phase A: A m0-3 + B n0-1, MFMA quadrant (m0-3 x n0-1) ----
#pragma unroll
        for (int m = 0; m < 4; ++m)
#pragma unroll
            for (int ks = 0; ks < 2; ++ks)
                a[m][ks] = LDF(As_, wr * 128 + m * 16 + fr, ks * 32 + kg);
#pragma unroll
        for (int n = 0; n < 2; ++n)
#pragma unroll
            for (int ks = 0; ks < 2; ++ks)
                b0[n][ks] = LDF(Bs_, wc * 64 + n * 16 + fr, ks * 32 + kg);
        __builtin_amdgcn_s_setprio(1);
#pragma unroll
        for (int ks = 0; ks < 2; ++ks)
#pragma unroll
            for (int m = 0; m < 4; ++m)
#pragma unroll
                for (int n = 0; n < 2; ++n)
                    acc[m][n] = __builtin_amdgcn_mfma_f32_16x16x32_bf16(
                        a[m][ks], b0[n][ks], acc[m][n], 0, 0, 0);
        __builtin_amdgcn_s_setprio(0);

        // ---- Phase B: B n2-3, MFMA (m0-3 x n2-3) ----
#pragma unroll
        for (int n = 0; n < 2; ++n)
#pragma unroll
            for (int ks = 0; ks < 2; ++ks)
                b1[n][ks] = LDF(Bs_, wc * 64 + (2 + n) * 16 + fr, ks * 32 + kg);
        __builtin_amdgcn_s_setprio(1);
#pragma unroll
        for (int ks = 0; ks < 2; ++ks)
#pragma unroll
            for (int m = 0; m < 4; ++m)
#pragma unroll
                for (int n = 0; n < 2; ++n)
                    acc[m][2 + n] = __builtin_amdgcn_mfma_f32_16x16x32_bf16(
                        a[m][ks], b1[n][ks], acc[m][2 + n], 0, 0, 0);
        __builtin_amdgcn_s_setprio(0);

        // ---- Phase C: A m4-7, MFMA (m4-7 x n2-3) ----
#pragma unroll
        for (int m = 0; m < 4; ++m)
#pragma unroll
            for (int ks = 0; ks < 2; ++ks)
                a[m][ks] = LDF(As_, wr * 128 + (4 + m) * 16 + fr, ks * 32 + kg);
        __builtin_amdgcn_s_setprio(1);
#pragma unroll
        for (int ks = 0; ks < 2; ++ks)
#pragma unroll
            for (int m = 0; m < 4; ++m)
#pragma unroll
                for (int n = 0; n < 2; ++n)
                    acc[4 + m][2 + n] = __builtin_amdgcn_mfma_f32_16x16x32_bf16(
                        a[m][ks], b1[n][ks], acc[4 + m][2 + n], 0, 0, 0);
        __builtin_amdgcn_s_setprio(0);

        // ---- Phase D: B n0-1 reload, MFMA (m4-7 x n0-1) ----
#pragma unroll
        for (int n = 0; n < 2; ++n)
#pragma unroll
            for (int ks = 0; ks < 2; ++ks)
                b0[n][ks] = LDF(Bs_, wc * 64 + n * 16 + fr, ks * 32 + kg);
        __builtin_amdgcn_s_setprio(1);
#pragma unroll
        for (int ks = 0; ks < 2; ++ks)
#pragma unroll
            for (int m = 0; m < 4; ++m)
#pragma unroll
                for (int n = 0; n < 2; ++n)
                    acc[4 + m][n] = __builtin_amdgcn_mfma_f32_16x16x32_bf16(
                        a[m][ks], b0[n][ks], acc[4 + m][n], 0, 0, 0);
        __builtin_amdgcn_s_setprio(0);

        if (ti == NT - 1) break;

        // all waves done reading buf[cur] (ds_reads consumed by MFMAs above)
        asm volatile("" ::: "memory");
        __builtin_amdgcn_s_barrier();
        if (ti + 2 < NT) {
            STAGE(cur, (ti + 2) * BK);                      // tile t+2 -> buf[cur]
            asm volatile("s_waitcnt vmcnt(8)" ::: "memory"); // tile t+1 landed
        } else {
            asm volatile("s_waitcnt vmcnt(0)" ::: "memory"); // drain tail
        }
        __builtin_amdgcn_s_barrier();                        // all waves see it
    }
#undef STAGE
#undef LDF

    // ---- epilogue: log-sigmoid + reduce ----
    // C/D layout: col = lane&15, row = (lane>>4)*4 + reg  (m89-verified)
    const int rbase = row0 + wr * 128 + ((lane >> 4) * 4);
    const int cbase = col0 + wc * 64 + fr;
    float s_all = 0.f, s_diag = 0.f;
#pragma unroll
    for (int m = 0; m < 8; ++m) {
#pragma unroll
        for (int n = 0; n < 4; ++n) {
#pragma unroll
            for (int r = 0; r < 4; ++r) {
                float S = acc[m][n][r];
                int row = rbase + m * 16 + r;
                int col = cbase + n * 16;
                bool dg = (row == col);
                float x = dg ? S : -S;
                float ll = fminf(x, 0.f) - __logf(1.f + __expf(-fabsf(x)));
                s_all += ll;
                if (dg) s_diag += ll;
            }
        }
    }

#pragma unroll
    for (int off = 32; off; off >>= 1) {
        s_all  += __shfl_down(s_all, off);
        s_diag += __shfl_down(s_diag, off);
    }
    __syncthreads();                    // waves drift out of the K-loop; resync before LDS reuse
    float* red = (float*)lds;
    if (lane == 0) { red[wid] = s_all; red[8 + wid] = s_diag; }
    __syncthreads();
    if (tid == 0) {
        float A = 0.f, D = 0.f;
#pragma unroll
        for (int w = 0; w < 8; ++w) { A += red[w]; D += red[8 + w]; }
        int bflat = bm * gridDim.x + bn;
        pall[bflat]  = A;
        pdiag[bflat] = D;
    }
}

// ---------------- Kernel 3: finalize ----------------
__global__ void finalize(const float* __restrict__ pall,
                         const float* __restrict__ pdiag,
                         float* __restrict__ out) {
    float a = 0.f, d = 0.f;
    for (int i = threadIdx.x; i < NBLK; i += 256) { a += pall[i]; d += pdiag[i]; }
#pragma unroll
    for (int off = 32; off; off >>= 1) {
        a += __shfl_down(a, off);
        d += __shfl_down(d, off);
    }
    __shared__ float r[8];
    int wid = threadIdx.x >> 6, lane = threadIdx.x & 63;
    if (lane == 0) { r[wid] = a; r[4 + wid] = d; }
    __syncthreads();
    if (threadIdx.x == 0) {
        float A = r[0] + r[1] + r[2] + r[3];
        float D = r[4] + r[5] + r[6] + r[7];
        out[0] = -(A + 39.f * D) / (float)BDIM;  // logLoss
        out[1] = -(40.f * D) / (float)BDIM;      // diagonalLoss
    }
}

extern "C" void kernel_launch(void* const* d_in, const int* in_sizes, int n_in,
                              void* d_out, int out_size, void* d_ws, size_t ws_size,
                              hipStream_t stream) {
    const float* enc = (const float*)d_in[0];
    const float* dec = (const float*)d_in[1];
    float* out = (float*)d_out;

    char* ws = (char*)d_ws;
    unsigned short* eb = (unsigned short*)ws;
    unsigned short* db = (unsigned short*)(ws + (size_t)16 * 1024 * 1024);
    float* pall  = (float*)(ws + (size_t)32 * 1024 * 1024);
    float* pdiag = pall + NBLK;

    reduce_cast<<<4096, 256, 0, stream>>>(
        (const float4*)enc, (const float4*)dec, (uint4*)eb, (uint4*)db);

    dim3 grid(BDIM / BN, BDIM / BM);  // (16, 16) = 256 blocks = 1/CU
    gemm_reduce<<<grid, 512, 0, stream>>>(eb, db, pall, pdiag);

    finalize<<<1, 256, 0, stream>>>(pall, pdiag, out);
}

// Round 3
// 95.017 us; speedup vs baseline: 1.2981x; 1.0027x over previous
//
#include <hip/hip_runtime.h>

// Problem: B=4096, D=2, H=2048.
// e = sum_d enc[b,d,h]; d = sum_d dec[b,d,h]; S = e @ d^T (4096x4096)
// M = S on diag, -S off diag; LL = log_sigmoid(M)
// logLoss = -(sum(LL) + 39*sum(diag LL))/B ; diagonalLoss = -40*sum(diag LL)/B

#define BDIM 4096
#define HDIM 2048
#define BM 256
#define BN 256
#define HK 32                       // half-tile K depth
#define NH (HDIM / HK)              // 64 half-tiles
#define NBLK ((BDIM/BM) * (BDIM/BN))  // 256 blocks

typedef __attribute__((ext_vector_type(8))) short bf16x8;
typedef __attribute__((ext_vector_type(4))) float f32x4;

__device__ __forceinline__ unsigned short f2bf(float f) {
    unsigned int u = __float_as_uint(f);
    unsigned int r = (u + 0x7FFFu + ((u >> 16) & 1u)) >> 16;
    return (unsigned short)r;
}

__device__ __forceinline__ void gll16(const void* g, void* l) {
    __builtin_amdgcn_global_load_lds(
        (const __attribute__((address_space(1))) unsigned int*)g,
        (__attribute__((address_space(3))) unsigned int*)l,
        16, 0, 0);
}

// ---------------- Kernel 1: D-reduce + cast to bf16 ----------------
__global__ void reduce_cast(const float4* __restrict__ enc,
                            const float4* __restrict__ dec,
                            uint4* __restrict__ eb,
                            uint4* __restrict__ db) {
    int idx = blockIdx.x * blockDim.x + threadIdx.x;   // 0..1048575
    int b  = idx >> 8;
    int ch = idx & 255;
    int f4 = b * 1024 + ch * 2;

    {
        float4 a0 = enc[f4],       a1 = enc[f4 + 1];
        float4 c0 = enc[f4 + 512], c1 = enc[f4 + 512 + 1];
        uint4 o;
        o.x = (unsigned int)f2bf(a0.x + c0.x) | ((unsigned int)f2bf(a0.y + c0.y) << 16);
        o.y = (unsigned int)f2bf(a0.z + c0.z) | ((unsigned int)f2bf(a0.w + c0.w) << 16);
        o.z = (unsigned int)f2bf(a1.x + c1.x) | ((unsigned int)f2bf(a1.y + c1.y) << 16);
        o.w = (unsigned int)f2bf(a1.z + c1.z) | ((unsigned int)f2bf(a1.w + c1.w) << 16);
        eb[idx] = o;
    }
    {
        float4 a0 = dec[f4],       a1 = dec[f4 + 1];
        float4 c0 = dec[f4 + 512], c1 = dec[f4 + 512 + 1];
        uint4 o;
        o.x = (unsigned int)f2bf(a0.x + c0.x) | ((unsigned int)f2bf(a0.y + c0.y) << 16);
        o.y = (unsigned int)f2bf(a0.z + c0.z) | ((unsigned int)f2bf(a0.w + c0.w) << 16);
        o.z = (unsigned int)f2bf(a1.x + c1.x) | ((unsigned int)f2bf(a1.y + c1.y) << 16);
        o.w = (unsigned int)f2bf(a1.z + c1.z) | ((unsigned int)f2bf(a1.w + c1.w) << 16);
        db[idx] = o;
    }
}

// ---------------- Kernel 2: 8-phase pipelined 256x256 GEMM + fused log-sigmoid ----------------
// 8 waves (2M x 4N), per-wave 128x64 output, acc[8][4] f32x4.
// LDS: ring of 4 slots, each A[256][32] + B[256][32] bf16 = 32 KiB -> 128 KiB.
// Per half-tile h (K=32): 2 phases of 16 MFMA; per phase issue 2 global_load_lds
// for slot h+3 (depth-3 prefetch); counted vmcnt(8) once per half-tile.
// Slot rotation swizzle: LDS 16B-slot = (global_slot + (row>>1)) & 3 (2-way banks).
__global__ __launch_bounds__(512, 2) void gemm_reduce(
        const unsigned short* __restrict__ eb,
        const unsigned short* __restrict__ db,
        float* __restrict__ pall,
        float* __restrict__ pdiag) {
    __shared__ __align__(16) unsigned short lds[4 * 16384];  // 128 KiB

    const int tid  = threadIdx.x;
    const int lane = tid & 63;
    const int wid  = tid >> 6;          // 0..7
    const int wr   = wid >> 2;          // 0..1  (M)
    const int wc   = wid & 3;           // 0..3  (N)
    const int bm   = blockIdx.y, bn = blockIdx.x;
    const int row0 = bm * BM, col0 = bn * BN;

    const int fr = lane & 15;                        // fragment row
    const int sl = ((lane >> 4) + (fr >> 1)) & 3;    // swizzled 16B slot (read side)

    // staging: thread t writes LDS linear (row = t>>2, slot = t&3) within an 8KB chunk;
    // inverse-rotated global source col so read-side rotation sees linear k.
    const int su = tid >> 2;                         // row in 128-row chunk
    const int sg = ((tid & 3) - (su >> 1)) & 3;      // global 16B slot this thread fetches

    f32x4 acc[8][4] = {};

#define STAGE_A(s, kt) {                                                        \
    gll16(eb + (size_t)(row0 + su) * HDIM + (kt) + sg * 8,                      \
          &lds[(s) * 16384 + tid * 8]);                                         \
    gll16(eb + (size_t)(row0 + 128 + su) * HDIM + (kt) + sg * 8,                \
          &lds[(s) * 16384 + 4096 + tid * 8]); }
#define STAGE_B(s, kt) {                                                        \
    gll16(db + (size_t)(col0 + su) * HDIM + (kt) + sg * 8,                      \
          &lds[(s) * 16384 + 8192 + tid * 8]);                                  \
    gll16(db + (size_t)(col0 + 128 + su) * HDIM + (kt) + sg * 8,                \
          &lds[(s) * 16384 + 8192 + 4096 + tid * 8]); }

    // prologue: slots 0,1,2 (12 loads in flight)
    STAGE_A(0, 0)  STAGE_B(0, 0)
    STAGE_A(1, HK) STAGE_B(1, HK)
    STAGE_A(2, 2 * HK) STAGE_B(2, 2 * HK)
    asm volatile("s_waitcnt vmcnt(8)" ::: "memory");   // slot 0 landed
    __builtin_amdgcn_s_barrier();

#pragma unroll 4
    for (int h = 0; h < NH; ++h) {
        const unsigned short* S = &lds[(h & 3) * 16384];
        bf16x8 af[4], bf[4];

        // ---- phase 0: ds A m0-3 + B n0-3; stage A-half of slot h+3; MFMA upper ----
#pragma unroll
        for (int m = 0; m < 4; ++m)
            af[m] = *(const bf16x8*)&S[(wr * 128 + m * 16 + fr) * 32 + sl * 8];
#pragma unroll
        for (int n = 0; n < 4; ++n)
            bf[n] = *(const bf16x8*)&S[8192 + (wc * 64 + n * 16 + fr) * 32 + sl * 8];
        if (h + 3 < NH) STAGE_A((h + 3) & 3, (h + 3) * HK)
        __builtin_amdgcn_s_barrier();
        asm volatile("s_waitcnt lgkmcnt(0)" ::: "memory");
        __builtin_amdgcn_sched_barrier(0);
        __builtin_amdgcn_s_setprio(1);
#pragma unroll
        for (int m = 0; m < 4; ++m)
#pragma unroll
            for (int n = 0; n < 4; ++n)
                acc[m][n] = __builtin_amdgcn_mfma_f32_16x16x32_bf16(
                    af[m], bf[n], acc[m][n], 0, 0, 0);
        __builtin_amdgcn_s_setprio(0);
        __builtin_amdgcn_s_barrier();

        // ---- phase 1: ds A m4-7; stage B-half of slot h+3; MFMA lower ----
#pragma unroll
        for (int m = 0; m < 4; ++m)
            af[m] = *(const bf16x8*)&S[(wr * 128 + (4 + m) * 16 + fr) * 32 + sl * 8];
        if (h + 3 < NH) STAGE_B((h + 3) & 3, (h + 3) * HK)
        __builtin_amdgcn_s_barrier();
        asm volatile("s_waitcnt lgkmcnt(0)" ::: "memory");
        __builtin_amdgcn_sched_barrier(0);
        __builtin_amdgcn_s_setprio(1);
#pragma unroll
        for (int m = 0; m < 4; ++m)
#pragma unroll
            for (int n = 0; n < 4; ++n)
                acc[4 + m][n] = __builtin_amdgcn_mfma_f32_16x16x32_bf16(
                    af[m], bf[n], acc[4 + m][n], 0, 0, 0);
        __builtin_amdgcn_s_setprio(0);
        // counted drain: slot h+1 must be landed before next iteration reads it
        if (h < NH - 3)       { asm volatile("s_waitcnt vmcnt(8)" ::: "memory"); }
        else if (h == NH - 3) { asm volatile("s_waitcnt vmcnt(4)" ::: "memory"); }
        else if (h == NH - 2) { asm volatile("s_waitcnt vmcnt(0)" ::: "memory"); }
        __builtin_amdgcn_s_barrier();
    }
#undef STAGE_A
#undef STAGE_B

    // ---- epilogue: log-sigmoid + reduce ----
    // C/D layout: col = lane&15, row = (lane>>4)*4 + reg  (m89-verified)
    const int rbase = row0 + wr * 128 + ((lane >> 4) * 4);
    const int cbase = col0 + wc * 64 + fr;
    float s_all = 0.f, s_diag = 0.f;
#pragma unroll
    for (int m = 0; m < 8; ++m) {
#pragma unroll
        for (int n = 0; n < 4; ++n) {
#pragma unroll
            for (int r = 0; r < 4; ++r) {
                float Sv = acc[m][n][r];
                int row = rbase + m * 16 + r;
                int col = cbase + n * 16;
                bool dg = (row == col);
                float x = dg ? Sv : -Sv;
                float ll = fminf(x, 0.f) - __logf(1.f + __expf(-fabsf(x)));
                s_all += ll;
                if (dg) s_diag += ll;
            }
        }
    }

#pragma unroll
    for (int off = 32; off; off >>= 1) {
        s_all  += __shfl_down(s_all, off);
        s_diag += __shfl_down(s_diag, off);
    }
    __syncthreads();                    // resync before LDS reuse
    float* red = (float*)lds;
    if (lane == 0) { red[wid] = s_all; red[8 + wid] = s_diag; }
    __syncthreads();
    if (tid == 0) {
        float A = 0.f, D = 0.f;
#pragma unroll
        for (int w = 0; w < 8; ++w) { A += red[w]; D += red[8 + w]; }
        int bflat = bm * gridDim.x + bn;
        pall[bflat]  = A;
        pdiag[bflat] = D;
    }
}

// ---------------- Kernel 3: finalize ----------------
__global__ void finalize(const float* __restrict__ pall,
                         const float* __restrict__ pdiag,
                         float* __restrict__ out) {
    float a = 0.f, d = 0.f;
    for (int i = threadIdx.x; i < NBLK; i += 256) { a += pall[i]; d += pdiag[i]; }
#pragma unroll
    for (int off = 32; off; off >>= 1) {
        a += __shfl_down(a, off);
        d += __shfl_down(d, off);
    }
    __shared__ float r[8];
    int wid = threadIdx.x >> 6, lane = threadIdx.x & 63;
    if (lane == 0) { r[wid] = a; r[4 + wid] = d; }
    __syncthreads();
    if (threadIdx.x == 0) {
        float A = r[0] + r[1] + r[2] + r[3];
        float D = r[4] + r[5] + r[6] + r[7];
        out[0] = -(A + 39.f * D) / (float)BDIM;  // logLoss
        out[1] = -(40.f * D) / (float)BDIM;      // diagonalLoss
    }
}

extern "C" void kernel_launch(void* const* d_in, const int* in_sizes, int n_in,
                              void* d_out, int out_size, void* d_ws, size_t ws_size,
                              hipStream_t stream) {
    const float* enc = (const float*)d_in[0];
    const float* dec = (const float*)d_in[1];
    float* out = (float*)d_out;

    char* ws = (char*)d_ws;
    unsigned short* eb = (unsigned short*)ws;
    unsigned short* db = (unsigned short*)(ws + (size_t)16 * 1024 * 1024);
    float* pall  = (float*)(ws + (size_t)32 * 1024 * 1024);
    float* pdiag = pall + NBLK;

    reduce_cast<<<4096, 256, 0, stream>>>(
        (const float4*)enc, (const float4*)dec, (uint4*)eb, (uint4*)db);

    dim3 grid(BDIM / BN, BDIM / BM);  // (16, 16) = 256 blocks = 1/CU
    gemm_reduce<<<grid, 512, 0, stream>>>(eb, db, pall, pdiag);

    finalize<<<1, 256, 0, stream>>>(pall, pdiag, out);
}